// Round 4
// baseline (129.705 us; speedup 1.0000x reference)
//
#include <hip/hip_runtime.h>

// DetectionLoss: NB=3, C=20, S=7, D=35, B=8192 -> 401408 cells, ~112 MB read.
// R4: wave-private double-buffered DMA pipeline, ZERO barriers.
// R3 (block-tile + __syncthreads) stalled at ~34us: every block drains
// vmcnt(0) at the barrier -> memory engine duty ~50%. Now each 64-thread
// block (1 wave) owns 2x17.9KB LDS buffers and grid-strides over 64-cell
// tiles: issue tile t+1 (18 DMAs) -> s_waitcnt vmcnt(18) (only t's DMAs,
// per-wave counter) -> compute t. Loads stay in flight continuously.

#define NBOX 3
#define NCLS 20
#define SDIM 7
#define DCH  35
#define WTILE 64                      // cells per wave-tile
#define OUT_UNITS (WTILE * DCH / 4)   // 560 float4 per tensor per tile
#define UNITS     (2 * OUT_UNITS)     // 1120 float4 per tile (out|tgt)

// s_waitcnt simm16 (gfx9/CDNA): vmcnt[3:0]=b3:0, expcnt=b6:4, lgkmcnt=b11:8, vmcnt[5:4]=b15:14
#define WAITCNT_VM18 0x4F72   // vmcnt=18, expcnt/lgkmcnt = no-wait
#define WAITCNT_VM0  0x0F70   // vmcnt=0,  expcnt/lgkmcnt = no-wait

typedef __attribute__((address_space(3))) unsigned int  lds_u32;
typedef const __attribute__((address_space(1))) unsigned int glob_u32;

__global__ __launch_bounds__(64) void detloss_kernel(
    const float* __restrict__ out_g, const float* __restrict__ tgt_g,
    float* __restrict__ partials, int n_tiles, float inv_nB)
{
    __shared__ float4 s_buf[2][UNITS];      // 35840 B -> 4 blocks(waves)/CU

    const int lane  = threadIdx.x;          // 0..63, one wave per block
    const int wid   = blockIdx.x;           // global wave id
    const int nwv   = gridDim.x;

    float lane_sum = 0.0f;

    // ---- DMA one tile (both tensors) into s_buf[buf]: 17 full + 1 half issue ----
    auto issue = [&](int tile, int buf) {
        const float4* go = (const float4*)out_g + (long long)tile * OUT_UNITS;
        const float4* gt = (const float4*)tgt_g + (long long)tile * OUT_UNITS;
        #pragma unroll
        for (int j = 0; j < 17; ++j) {
            const int k = j * 64 + lane;
            const float4* src = (k < OUT_UNITS) ? (go + k) : (gt + (k - OUT_UNITS));
            __builtin_amdgcn_global_load_lds((glob_u32*)src, (lds_u32*)&s_buf[buf][k], 16, 0, 0);
        }
        if (lane < 32) {
            const int k = 17 * 64 + lane;   // 1088..1119 -> tgt units 528..559
            __builtin_amdgcn_global_load_lds((glob_u32*)(gt + (k - OUT_UNITS)),
                                             (lds_u32*)&s_buf[buf][k], 16, 0, 0);
        }
    };

    auto compute = [&](int buf) {
        const float* sf = (const float*)&s_buf[buf][0];
        const float* o  = sf + lane * DCH;                  // out: cell = lane
        const float* g  = sf + 4 * OUT_UNITS + lane * DCH;  // tgt section

        // target box (box 0) -> xyxy, exactly as reference
        const float tx  = g[0] / 7.0f, ty = g[1] / 7.0f;
        const float thw = 0.5f * g[2], thh = 0.5f * g[3];
        const float tx1 = tx - thw, ty1 = ty - thh;
        const float tx2 = tx + thw, ty2 = ty + thh;
        const float a2  = (tx2 - tx1) * (ty2 - ty1);

        const float conf_t = g[4];
        const float obj    = (conf_t == 1.0f) ? 1.0f : 0.0f;
        const float noobj  = (conf_t == 0.0f) ? 1.0f : 0.0f;

        int   best = 0;
        float biou = -__builtin_inff();   // strict > => first-index-wins (matches argmax)
        float conf_sq = 0.0f;

        #pragma unroll
        for (int i = 0; i < NBOX; ++i) {
            const float px  = o[5*i]   / 7.0f;
            const float py  = o[5*i+1] / 7.0f;
            const float phw = 0.5f * o[5*i+2];
            const float phh = 0.5f * o[5*i+3];
            const float px1 = px - phw, py1 = py - phh;
            const float px2 = px + phw, py2 = py + phh;

            const float ltx = fmaxf(px1, tx1), lty = fmaxf(py1, ty1);
            const float rbx = fminf(px2, tx2), rby = fminf(py2, ty2);
            const float w = fmaxf(rbx - ltx, 0.0f);
            const float h = fmaxf(rby - lty, 0.0f);
            const float inter = w * h;
            const float a1 = (px2 - px1) * (py2 - py1);
            const float iou = inter / (a1 + a2 - inter);
            if (iou > biou) { biou = iou; best = i; }

            const float dc = o[5*i+4] - g[5*i+4];
            conf_sq += dc * dc;
        }

        float loss = 0.5f * noobj * conf_sq;

        const int b5 = 5 * best;
        const float dx = o[b5]   - g[b5];
        const float dy = o[b5+1] - g[b5+1];
        const float xyl = dx*dx + dy*dy;
        const float dw = sqrtf(o[b5+2]) - sqrtf(g[b5+2]);
        const float dh = sqrtf(o[b5+3]) - sqrtf(g[b5+3]);
        const float whl = dw*dw + dh*dh;
        const float dcf = o[b5+4] - biou;
        const float contain = dcf * dcf;

        float cls = 0.0f;
        #pragma unroll
        for (int c = 0; c < NCLS; ++c) {
            const float d = o[5*NBOX + c] - g[5*NBOX + c];
            cls += d * d;
        }

        lane_sum += loss + obj * (5.0f * (xyl + whl) + contain + cls);
    };

    // ---- double-buffered pipeline, no barriers ----
    int cur = wid;
    if (cur < n_tiles) {
        issue(cur, 0);
        int buf = 0;
        for (int nxt = cur + nwv; nxt < n_tiles; nxt += nwv) {
            issue(nxt, buf ^ 1);                    // 18 new DMAs in flight
            __builtin_amdgcn_s_waitcnt(WAITCNT_VM18); // previous tile's 18 done
            __asm__ __volatile__("" ::: "memory");  // no LDS-read hoist / CSE
            compute(buf);
            buf ^= 1;
        }
        __builtin_amdgcn_s_waitcnt(WAITCNT_VM0);
        __asm__ __volatile__("" ::: "memory");
        compute(buf);
    }

    // ---- wave reduce -> one partial per wave ----
    float v = lane_sum * inv_nB;
    #pragma unroll
    for (int off = 32; off > 0; off >>= 1)
        v += __shfl_down(v, off);
    if (lane == 0) partials[wid] = v;
}

__global__ __launch_bounds__(1024) void reduce_kernel(
    const float* __restrict__ partials, float* __restrict__ out, int n)
{
    __shared__ float s[1024 / 64];
    float v = (threadIdx.x < n) ? partials[threadIdx.x] : 0.0f;
    #pragma unroll
    for (int off = 32; off > 0; off >>= 1)
        v += __shfl_down(v, off);
    if ((threadIdx.x & 63) == 0) s[threadIdx.x >> 6] = v;
    __syncthreads();
    if (threadIdx.x == 0) {
        float t = 0.0f;
        #pragma unroll
        for (int w = 0; w < 1024 / 64; ++w) t += s[w];
        out[0] = t;
    }
}

extern "C" void kernel_launch(void* const* d_in, const int* in_sizes, int n_in,
                              void* d_out, int out_size, void* d_ws, size_t ws_size,
                              hipStream_t stream) {
    const float* out_p = (const float*)d_in[0];
    const float* tgt_p = (const float*)d_in[1];
    float* res  = (float*)d_out;
    float* part = (float*)d_ws;

    const int n_cells = in_sizes[0] / DCH;            // 401408
    const int nB = n_cells / (SDIM * SDIM);           // 8192
    const float inv_nB = 1.0f / (float)nB;
    const int n_tiles = n_cells / WTILE;              // 6272 (exact)

    const int nblocks = 1024;                         // 1024 waves, 4/CU (LDS-capped)
    hipLaunchKernelGGL(detloss_kernel, dim3(nblocks), dim3(64), 0, stream,
                       out_p, tgt_p, part, n_tiles, inv_nB);
    hipLaunchKernelGGL(reduce_kernel, dim3(1), dim3(1024), 0, stream,
                       part, res, nblocks);
}